// Round 5
// baseline (716.559 us; speedup 1.0000x reference)
//
#include <hip/hip_runtime.h>
#include <math.h>

#define T_DATA 50000
#define N_E 2000
#define N_I 200
#define SUB_NO 20
#define T_NO 401
#define KP 404            // zero-padded kernel length (multiple of 4)
#define EXP_NO 81
#define HID_NO 6
#define ROWS 16           // rows per k_seg block (50000 = 3125 * 16)

// ---- workspace layout (float offsets) ----
#define WS_SYN_ET   0              // [20][T]
#define WS_SYN_IT   1000000        // [20][T]
#define WS_SYNT     2000000        // [20][T]  E-conv + I-conv sum
#define WS_H        3000000        // [6][T]
#define WS_PART     3300000        // [6][T]
#define WS_KE       3600000        // [20][404]
#define WS_KI       3608080        // [20][404]
#define WS_K1       3616160        // [6][404]
#define WS_K2       3618584       // [6][404]
#define WS_SPK      3621008        // [404]
#define WS_ASGE     3621412        // uint[512]  packed uchar asg (2048 cols, pad=20)
#define WS_ASGI     3621924        // uint[64]   packed uchar asg (256 cols, pad=20)

__device__ __forceinline__ float ftanh(float x) {
  // tanh(x) = 1 - 2/(e^{2x}+1); exact at +-inf, ~1e-6 abs err, no branches
  float e = __expf(2.f * x);
  return 1.f - 2.f * __builtin_amdgcn_rcpf(e + 1.f);
}

// Fire-and-forget LDS float add. Low 32 bits of a generic pointer to LDS are
// the LDS byte offset (aperture is 4GB-aligned), which is what ds_add_f32
// takes. No return value -> no read-modify-write latency chain.
__device__ __forceinline__ void ds_addf(float* p, float v) {
  asm volatile("ds_add_f32 %0, %1"
               :: "v"((unsigned int)(unsigned long long)p), "v"(v));
}

// ============================================================ prep
__global__ __launch_bounds__(256) void k_prep(
    const float* __restrict__ W_syn, const float* __restrict__ Tau_syn,
    const float* __restrict__ Delta_syn, const float* __restrict__ W_spk,
    const float* __restrict__ Tau_spk, const float* __restrict__ W_root_1,
    const float* __restrict__ W_root_2, const float* __restrict__ C_syn_e,
    const float* __restrict__ C_syn_i, const float* __restrict__ exp_basis,
    float* __restrict__ ws, unsigned int* __restrict__ asg_e,
    unsigned int* __restrict__ asg_i, float* __restrict__ out_filters) {
  const int bid = blockIdx.x, tid = threadIdx.x;
  if (bid == 0) {                       // packed synapse->subunit assignment (E)
    for (int u = tid; u < 512; u += 256) {
      unsigned int p = 0;
      for (int jj = 0; jj < 4; ++jj) {
        const int e = u * 4 + jj;
        int a = 20;                     // dummy slot for padded columns
        if (e < N_E) {
          a = 0;
          for (int s = 0; s < SUB_NO; ++s) if (C_syn_e[s * N_E + e] > 0.5f) a = s;
        }
        p |= (unsigned int)a << (8 * jj);
      }
      asg_e[u] = p;
    }
  } else if (bid == 1) {                // packed assignment (I)
    for (int u = tid; u < 64; u += 256) {
      unsigned int p = 0;
      for (int jj = 0; jj < 4; ++jj) {
        const int e = u * 4 + jj;
        int a = 20;
        if (e < N_I) {
          a = 0;
          for (int s = 0; s < SUB_NO; ++s) if (C_syn_i[s * N_I + e] > 0.5f) a = s;
        }
        p |= (unsigned int)a << (8 * jj);
      }
      asg_i[u] = p;
    }
  } else if (bid == 2) {                // spike-history kernel
    const float tau = Tau_spk[0], w = W_spk[0];
    const float it2 = 1.f / (tau * tau);
    for (int t = tid; t < KP; t += 256) {
      float v = 0.f;
      if (t < T_NO) { float tt = (float)t * it2; v = tt * __expf(-tt) * w * w; }
      ws[WS_SPK + t] = v;
    }
  } else if (bid < 3 + SUB_NO) {        // synaptic E/I kernels + out_filters
    const int s = bid - 3;
    const float we = W_syn[s * 2], wi = W_syn[s * 2 + 1];
    const float te = Tau_syn[s * 2], ti = Tau_syn[s * 2 + 1];
    const float de = Delta_syn[s * 2], di = Delta_syn[s * 2 + 1];
    const float ie2 = 1.f / (te * te), ii2 = 1.f / (ti * ti);
    for (int t = tid; t < KP; t += 256) {
      float ve = 0.f, vi = 0.f;
      if (t < T_NO) {
        float xe = fmaxf((float)t - de, 0.f) * ie2;
        float xi = fmaxf((float)t - di, 0.f) * ii2;
        ve = xe * __expf(-xe) * we * we;
        vi = -(xi * __expf(-xi) * wi * wi);
        out_filters[s * T_NO + t] = ve;
        out_filters[(SUB_NO + s) * T_NO + t] = vi;
      }
      ws[WS_KE + s * KP + t] = ve;
      ws[WS_KI + s * KP + t] = vi;
    }
  } else {                              // root conv kernels K1,K2 = W_root @ exp_basis
    const int h = bid - (3 + SUB_NO);   // 0..5
    for (int t = tid; t < KP; t += 256) {
      float v1 = 0.f, v2 = 0.f;
      if (t < T_NO) {
        for (int b = 0; b < EXP_NO; ++b) {
          float bb = exp_basis[b * T_NO + t];
          v1 = fmaf(W_root_1[h * EXP_NO + b], bb, v1);
          v2 = fmaf(W_root_2[h * EXP_NO + b], bb, v2);
        }
      }
      ws[WS_K1 + h * KP + t] = v1;
      ws[WS_K2 + h * KP + t] = v2;
    }
  }
}

// ============================================================ segmented sums
// Perfectly coalesced loads (consecutive lanes -> consecutive float4, 1 KB per
// wave instruction) + fire-and-forget ds_add_f32 into tiny per-row LDS slots.
// No read-modify-write chains, no reduction phase, 5 KB LDS -> 8 blocks/CU.
__global__ __launch_bounds__(256) void k_seg(
    const float* __restrict__ S_e, const float* __restrict__ S_i,
    const unsigned int* __restrict__ asg_e, const unsigned int* __restrict__ asg_i,
    float* __restrict__ syn_eT, float* __restrict__ syn_iT) {
  __shared__ float accE[ROWS][21];   // slot 20 = dummy for padded cols
  __shared__ float accI[ROWS][21];
  __shared__ unsigned int asgl[576];
  const int tid = threadIdx.x;
  const int t0 = blockIdx.x * ROWS;

  for (int i = tid; i < 512; i += 256) asgl[i] = asg_e[i];
  if (tid < 64) asgl[512 + tid] = asg_i[tid];
  for (int i = tid; i < ROWS * 21; i += 256) {
    ((float*)accE)[i] = 0.f;
    ((float*)accI)[i] = 0.f;
  }
  __syncthreads();

  // ---- excitatory: 16 rows x 512 virtual float4 (2048 cols, pad slot 20)
  {
    const float* se = S_e + (size_t)t0 * N_E;
    #pragma unroll 4
    for (int k = 0; k < 32; ++k) {
      const int g = tid + k * 256;
      const int row = g >> 9, c4 = g & 511;
      const int col = c4 * 4;
      float4 v = make_float4(0.f, 0.f, 0.f, 0.f);
      if (col < N_E) v = *(const float4*)(se + (size_t)row * N_E + col);
      const unsigned int a = asgl[c4];
      ds_addf(&accE[row][a & 255], v.x);
      ds_addf(&accE[row][(a >> 8) & 255], v.y);
      ds_addf(&accE[row][(a >> 16) & 255], v.z);
      ds_addf(&accE[row][a >> 24], v.w);
    }
  }
  // ---- inhibitory: 16 rows x 64 virtual float4 (256 cols, pad slot 20)
  {
    const float* si = S_i + (size_t)t0 * N_I;
    #pragma unroll
    for (int k = 0; k < 4; ++k) {
      const int g = tid + k * 256;
      const int row = g >> 6, c4 = g & 63;
      const int col = c4 * 4;
      float4 v = make_float4(0.f, 0.f, 0.f, 0.f);
      if (col < N_I) v = *(const float4*)(si + (size_t)row * N_I + col);
      const unsigned int a = asgl[512 + c4];
      ds_addf(&accI[row][a & 255], v.x);
      ds_addf(&accI[row][(a >> 8) & 255], v.y);
      ds_addf(&accI[row][(a >> 16) & 255], v.z);
      ds_addf(&accI[row][a >> 24], v.w);
    }
  }
  // asm DS ops are invisible to the compiler's waitcnt insertion
  asm volatile("s_waitcnt lgkmcnt(0)" ::: "memory");
  __syncthreads();

  for (int o = tid; o < ROWS * SUB_NO; o += 256) {
    const int row = o & 15, s = o >> 4;
    syn_eT[s * T_DATA + t0 + row] = accE[row][s];
    syn_iT[s * T_DATA + t0 + row] = accI[row][s];
  }
}

// ============================================================ conv machinery
// out[t] = sum_j K[j] * X[t + S - j], K zero-padded to 404 taps.
template <int NOUT>
__device__ __forceinline__ void conv_acc(const float* __restrict__ xl,
                                         const float* __restrict__ kg,
                                         int lt, float* __restrict__ acc) {
  constexpr int NW = NOUT + 4;
  float xw[NW];
  #pragma unroll
  for (int r = 0; r < NW / 4; ++r) {
    float4 v = *(const float4*)(xl + lt + 400 + 4 * r);
    xw[4 * r + 0] = v.x; xw[4 * r + 1] = v.y;
    xw[4 * r + 2] = v.z; xw[4 * r + 3] = v.w;
  }
  const float* kp = kg;
  for (int g = 0; g < 100; ++g) {
    float4 kv = *(const float4*)kp; kp += 4;   // uniform -> scalar load
    float kw[4] = {kv.x, kv.y, kv.z, kv.w};
    #pragma unroll
    for (int m = 0; m < 4; ++m)
      #pragma unroll
      for (int j = 0; j < NOUT; ++j)
        acc[j] = fmaf(kw[m], xw[4 + j - m], acc[j]);
    #pragma unroll
    for (int i = NW - 1; i >= 4; --i) xw[i] = xw[i - 4];
    float4 nv = *(const float4*)(xl + lt + 396 - 4 * g);
    xw[0] = nv.x; xw[1] = nv.y; xw[2] = nv.z; xw[3] = nv.w;
  }
  { // final tap group g = 100 (taps 400..403, 401..403 are zero)
    float4 kv = *(const float4*)kp;
    float kw[4] = {kv.x, kv.y, kv.z, kv.w};
    #pragma unroll
    for (int m = 0; m < 4; ++m)
      #pragma unroll
      for (int j = 0; j < NOUT; ++j)
        acc[j] = fmaf(kw[m], xw[4 + j - m], acc[j]);
  }
}

__device__ __forceinline__ void fill_tile(float* __restrict__ xl,
                                          const float* __restrict__ X,
                                          int o, int n) {
  for (int i = threadIdx.x; i < n; i += blockDim.x) {
    int g = o + i;
    xl[i] = (g >= 0 && g < T_DATA) ? X[g] : 0.f;
  }
}

// ---- per-subunit synaptic conv: synT[s][t] = (ke*syn_e)[t] + (ki*syn_i)[t]
__global__ __launch_bounds__(256) void k_syn_conv(
    const float* __restrict__ syn_eT, const float* __restrict__ syn_iT,
    const float* __restrict__ ws, float* __restrict__ synT) {
  const int s = blockIdx.y;
  const int t0 = blockIdx.x * 2048;
  __shared__ __align__(16) float xe[2456];
  __shared__ __align__(16) float xi[2456];
  fill_tile(xe, syn_eT + s * T_DATA, t0 - 404, 2452);
  fill_tile(xi, syn_iT + s * T_DATA, t0 - 404, 2452);
  __syncthreads();
  const int lt = threadIdx.x * 8;
  float acc[8] = {0, 0, 0, 0, 0, 0, 0, 0};
  conv_acc<8>(xe, ws + WS_KE + s * KP, lt, acc);
  conv_acc<8>(xi, ws + WS_KI + s * KP, lt, acc);
  const int t = t0 + lt;
  #pragma unroll
  for (int j = 0; j < 8; ++j)
    if (t + j < T_DATA) synT[s * T_DATA + t + j] = acc[j];
}

// ---- root conv layer 1 with inlined binary-tree tanh recursion.
// Each block recomputes h0 = tree(synT) for its (haloed) window, then convs.
__global__ __launch_bounds__(256) void k_root1tree(
    const float* __restrict__ synT, const float* __restrict__ Theta,
    const float* __restrict__ W_sub, const float* __restrict__ ws,
    float* __restrict__ h_ws) {
  const int c = blockIdx.y;
  const int t0 = blockIdx.x * 1024;
  __shared__ __align__(16) float xt[1432];
  const int o = t0 + 200 - 404;
  for (int i = threadIdx.x; i < 1428; i += 256) {
    const int t = o + i;
    float h = 0.f;
    if (t >= 0 && t < T_DATA) {
      float ns[SUB_NO];
      #pragma unroll
      for (int q = SUB_NO - 1; q >= 1; --q) {
        float x = synT[q * T_DATA + t] + Theta[q];
        const int c1 = 2 * q + 1, c2 = 2 * q + 2;
        if (c1 < SUB_NO) { float w = W_sub[c1]; x = fmaf(w * w, ns[c1], x); }
        if (c2 < SUB_NO) { float w = W_sub[c2]; x = fmaf(w * w, ns[c2], x); }
        ns[q] = ftanh(x);
      }
      const float w1 = W_sub[1], w2 = W_sub[2];
      h = ftanh(synT[t] + Theta[0] + w1 * w1 * ns[1] + w2 * w2 * ns[2]);
    }
    xt[i] = h;
  }
  __syncthreads();
  const int lt = threadIdx.x * 4;
  float acc[4] = {0, 0, 0, 0};
  conv_acc<4>(xt, ws + WS_K1 + c * KP, lt, acc);
  const int t = t0 + lt;
  #pragma unroll
  for (int j = 0; j < 4; ++j)
    if (t + j < T_DATA) h_ws[c * T_DATA + t + j] = ftanh(acc[j]);
}

// ---- root conv layer 2 partials (y<6) + spike-history conv (y==6)
__global__ __launch_bounds__(256) void k_root2spk(
    const float* __restrict__ h_ws, const float* __restrict__ Z,
    const float* __restrict__ ws, float* __restrict__ part,
    float* __restrict__ outV) {
  const int c = blockIdx.y;
  const int t0 = blockIdx.x * 1024;
  __shared__ __align__(16) float xt[1432];
  const int lt = threadIdx.x * 4;
  float acc[4] = {0, 0, 0, 0};
  if (c < HID_NO) {
    fill_tile(xt, h_ws + c * T_DATA, t0 + 200 - 404, 1428);
    __syncthreads();
    conv_acc<4>(xt, ws + WS_K2 + c * KP, lt, acc);
    const int t = t0 + lt;
    #pragma unroll
    for (int j = 0; j < 4; ++j)
      if (t + j < T_DATA) part[c * T_DATA + t + j] = acc[j];
  } else {
    fill_tile(xt, Z, t0 - 1 - 404, 1428);
    __syncthreads();
    conv_acc<4>(xt, ws + WS_SPK, lt, acc);
    const int t = t0 + lt;
    #pragma unroll
    for (int j = 0; j < 4; ++j)
      if (t + j < T_DATA) outV[t + j] = acc[j];
  }
}

// ---- combine channels + sigmoid -> final_Z
__global__ __launch_bounds__(256) void k_comb(
    const float* __restrict__ part, float* __restrict__ outZ) {
  const int t = blockIdx.x * 256 + threadIdx.x;
  if (t >= T_DATA) return;
  float v = 0.f;
  #pragma unroll
  for (int c = 0; c < HID_NO; ++c) v += part[c * T_DATA + t];
  outZ[t] = __builtin_amdgcn_rcpf(1.f + __expf(-v));
}

// ============================================================ launch
extern "C" void kernel_launch(void* const* d_in, const int* in_sizes, int n_in,
                              void* d_out, int out_size, void* d_ws, size_t ws_size,
                              hipStream_t stream) {
  const float* S_e      = (const float*)d_in[0];
  const float* S_i      = (const float*)d_in[1];
  const float* Z        = (const float*)d_in[2];
  const float* W_syn    = (const float*)d_in[3];
  const float* Tau_syn  = (const float*)d_in[4];
  const float* Delta_syn= (const float*)d_in[5];
  const float* W_sub    = (const float*)d_in[6];
  const float* W_spk    = (const float*)d_in[7];
  const float* Tau_spk  = (const float*)d_in[8];
  const float* Theta    = (const float*)d_in[9];
  const float* W_root_1 = (const float*)d_in[10];
  const float* W_root_2 = (const float*)d_in[11];
  // d_in[12] = C_den (tree structure is fixed by construction; hardcoded)
  const float* C_syn_e  = (const float*)d_in[13];
  const float* C_syn_i  = (const float*)d_in[14];
  const float* exp_basis= (const float*)d_in[15];

  float* ws = (float*)d_ws;
  unsigned int* asg_e = (unsigned int*)(ws + WS_ASGE);
  unsigned int* asg_i = (unsigned int*)(ws + WS_ASGI);
  float* out = (float*)d_out;          // [V(50000) | Z(50000) | filters(16040)]

  k_prep<<<3 + SUB_NO + HID_NO, 256, 0, stream>>>(
      W_syn, Tau_syn, Delta_syn, W_spk, Tau_spk, W_root_1, W_root_2,
      C_syn_e, C_syn_i, exp_basis, ws, asg_e, asg_i, out + 2 * T_DATA);

  k_seg<<<T_DATA / ROWS, 256, 0, stream>>>(
      S_e, S_i, asg_e, asg_i, ws + WS_SYN_ET, ws + WS_SYN_IT);

  k_syn_conv<<<dim3(25, SUB_NO), 256, 0, stream>>>(
      ws + WS_SYN_ET, ws + WS_SYN_IT, ws, ws + WS_SYNT);

  k_root1tree<<<dim3(49, HID_NO), 256, 0, stream>>>(
      ws + WS_SYNT, Theta, W_sub, ws, ws + WS_H);

  k_root2spk<<<dim3(49, HID_NO + 1), 256, 0, stream>>>(
      ws + WS_H, Z, ws, ws + WS_PART, out);

  k_comb<<<(T_DATA + 255) / 256, 256, 0, stream>>>(ws + WS_PART, out + T_DATA);
}

// Round 7
// 701.925 us; speedup vs baseline: 1.0208x; 1.0208x over previous
//
#include <hip/hip_runtime.h>
#include <math.h>

#define T_DATA 50000
#define N_E 2000
#define N_I 200
#define SUB_NO 20
#define T_NO 401
#define KP 404            // zero-padded kernel length (multiple of 4)
#define EXP_NO 81
#define HID_NO 6
#define ROWS 16           // rows per k_seg block (50000 = 3125 * 16)

// ---- workspace layout (float offsets) ----
#define WS_SYN_ET   0              // [20][T]
#define WS_SYN_IT   1000000        // [20][T]
#define WS_SYNT     2000000        // [20][T]  E-conv + I-conv sum
#define WS_H        3000000        // [6][T]
#define WS_PART     3300000        // [6][T]
#define WS_KE       3600000        // [20][404]
#define WS_KI       3608080        // [20][404]
#define WS_K1       3616160        // [6][404]
#define WS_K2       3618584        // [6][404]
#define WS_SPK      3621008        // [404]
#define WS_ASGE     3621412        // uint[512]  packed uchar asg (2048 cols, pad=20)
#define WS_ASGI     3621924        // uint[64]   packed uchar asg (256 cols, pad=20)

__device__ __forceinline__ float ftanh(float x) {
  // tanh(x) = 1 - 2/(e^{2x}+1); exact at +-inf, ~1e-6 abs err, no branches
  float e = __expf(2.f * x);
  return 1.f - 2.f * __builtin_amdgcn_rcpf(e + 1.f);
}

// Fire-and-forget LDS float add (mechanism proven correct in R5). Safe ONLY
// when each address is touched by a single thread (no same-address
// serialization). No return value -> no read-modify-write latency chain.
__device__ __forceinline__ void ds_addf(float* p, float v) {
  asm volatile("ds_add_f32 %0, %1"
               :: "v"((unsigned int)(unsigned long long)p), "v"(v));
}

// ============================================================ prep
__global__ __launch_bounds__(256) void k_prep(
    const float* __restrict__ W_syn, const float* __restrict__ Tau_syn,
    const float* __restrict__ Delta_syn, const float* __restrict__ W_spk,
    const float* __restrict__ Tau_spk, const float* __restrict__ W_root_1,
    const float* __restrict__ W_root_2, const float* __restrict__ C_syn_e,
    const float* __restrict__ C_syn_i, const float* __restrict__ exp_basis,
    float* __restrict__ ws, unsigned int* __restrict__ asg_e,
    unsigned int* __restrict__ asg_i, float* __restrict__ out_filters) {
  const int bid = blockIdx.x, tid = threadIdx.x;
  if (bid == 0) {                       // packed synapse->subunit assignment (E)
    for (int u = tid; u < 512; u += 256) {
      unsigned int p = 0;
      for (int jj = 0; jj < 4; ++jj) {
        const int e = u * 4 + jj;
        int a = 20;                     // dummy slot for padded columns
        if (e < N_E) {
          a = 0;
          for (int s = 0; s < SUB_NO; ++s) if (C_syn_e[s * N_E + e] > 0.5f) a = s;
        }
        p |= (unsigned int)a << (8 * jj);
      }
      asg_e[u] = p;
    }
  } else if (bid == 1) {                // packed assignment (I)
    for (int u = tid; u < 64; u += 256) {
      unsigned int p = 0;
      for (int jj = 0; jj < 4; ++jj) {
        const int e = u * 4 + jj;
        int a = 20;
        if (e < N_I) {
          a = 0;
          for (int s = 0; s < SUB_NO; ++s) if (C_syn_i[s * N_I + e] > 0.5f) a = s;
        }
        p |= (unsigned int)a << (8 * jj);
      }
      asg_i[u] = p;
    }
  } else if (bid == 2) {                // spike-history kernel
    const float tau = Tau_spk[0], w = W_spk[0];
    const float it2 = 1.f / (tau * tau);
    for (int t = tid; t < KP; t += 256) {
      float v = 0.f;
      if (t < T_NO) { float tt = (float)t * it2; v = tt * __expf(-tt) * w * w; }
      ws[WS_SPK + t] = v;
    }
  } else if (bid < 3 + SUB_NO) {        // synaptic E/I kernels + out_filters
    const int s = bid - 3;
    const float we = W_syn[s * 2], wi = W_syn[s * 2 + 1];
    const float te = Tau_syn[s * 2], ti = Tau_syn[s * 2 + 1];
    const float de = Delta_syn[s * 2], di = Delta_syn[s * 2 + 1];
    const float ie2 = 1.f / (te * te), ii2 = 1.f / (ti * ti);
    for (int t = tid; t < KP; t += 256) {
      float ve = 0.f, vi = 0.f;
      if (t < T_NO) {
        float xe = fmaxf((float)t - de, 0.f) * ie2;
        float xi = fmaxf((float)t - di, 0.f) * ii2;
        ve = xe * __expf(-xe) * we * we;
        vi = -(xi * __expf(-xi) * wi * wi);
        out_filters[s * T_NO + t] = ve;
        out_filters[(SUB_NO + s) * T_NO + t] = vi;
      }
      ws[WS_KE + s * KP + t] = ve;
      ws[WS_KI + s * KP + t] = vi;
    }
  } else {                              // root conv kernels K1,K2 = W_root @ exp_basis
    const int h = bid - (3 + SUB_NO);   // 0..5
    for (int t = tid; t < KP; t += 256) {
      float v1 = 0.f, v2 = 0.f;
      if (t < T_NO) {
        for (int b = 0; b < EXP_NO; ++b) {
          float bb = exp_basis[b * T_NO + t];
          v1 = fmaf(W_root_1[h * EXP_NO + b], bb, v1);
          v2 = fmaf(W_root_2[h * EXP_NO + b], bb, v2);
        }
      }
      ws[WS_K1 + h * KP + t] = v1;
      ws[WS_K2 + h * KP + t] = v2;
    }
  }
}

// ============================================================ segmented sums
// Thread (r=tid>>4, sub=tid&15) owns row t0+r, cols [sub*16, sub*16+16) of
// each 256-col chunk (each lane consumes whole 64B lines, every line fetched
// once). EXCLUSIVE per-thread 44-slot LDS accumulator (E: 0..20, I: 22..42)
// updated with fire-and-forget ds_add_f32: no RMW chains, no collisions.
__global__ __launch_bounds__(256) void k_seg(
    const float* __restrict__ S_e, const float* __restrict__ S_i,
    const unsigned int* __restrict__ asg_e, const unsigned int* __restrict__ asg_i,
    float* __restrict__ syn_eT, float* __restrict__ syn_iT) {
  __shared__ float acc[256 * 44];        // 45 KB
  __shared__ unsigned int asgl[576];
  const int tid = threadIdx.x;
  const int t0 = blockIdx.x * ROWS;
  const int r = tid >> 4, sub = tid & 15;
  float* __restrict__ myacc = acc + tid * 44;
  const float4 z4 = make_float4(0.f, 0.f, 0.f, 0.f);

  for (int i = tid; i < 512; i += 256) asgl[i] = asg_e[i];
  if (tid < 64) asgl[512 + tid] = asg_i[tid];
  #pragma unroll
  for (int i = 0; i < 11; ++i) *(float4*)(myacc + 4 * i) = z4;
  __syncthreads();

  // ---- excitatory: 8 chunks of 256 virtual cols
  const float* rowp = S_e + (size_t)(t0 + r) * N_E;
  #pragma unroll
  for (int ch = 0; ch < 8; ++ch) {
    const int col0 = ch * 256 + sub * 16;
    float4 v[4];
    #pragma unroll
    for (int j = 0; j < 4; ++j) {
      const int col = col0 + j * 4;
      v[j] = (col + 4 <= N_E) ? *(const float4*)(rowp + col) : z4;
    }
    #pragma unroll
    for (int j = 0; j < 4; ++j) {
      const unsigned int a = asgl[ch * 64 + sub * 4 + j];
      ds_addf(&myacc[a & 255], v[j].x);
      ds_addf(&myacc[(a >> 8) & 255], v[j].y);
      ds_addf(&myacc[(a >> 16) & 255], v[j].z);
      ds_addf(&myacc[a >> 24], v[j].w);
    }
  }
  // ---- inhibitory: 1 chunk (200 cols, pad to 256)
  {
    const float* rowpI = S_i + (size_t)(t0 + r) * N_I;
    const int col0 = sub * 16;
    float4 v[4];
    #pragma unroll
    for (int j = 0; j < 4; ++j) {
      const int col = col0 + j * 4;
      v[j] = (col + 4 <= N_I) ? *(const float4*)(rowpI + col) : z4;
    }
    #pragma unroll
    for (int j = 0; j < 4; ++j) {
      const unsigned int a = asgl[512 + sub * 4 + j];
      ds_addf(&myacc[22 + (a & 255)], v[j].x);
      ds_addf(&myacc[22 + ((a >> 8) & 255)], v[j].y);
      ds_addf(&myacc[22 + ((a >> 16) & 255)], v[j].z);
      ds_addf(&myacc[22 + (a >> 24)], v[j].w);
    }
  }
  // asm DS ops are invisible to the compiler's waitcnt insertion
  asm volatile("s_waitcnt lgkmcnt(0)" ::: "memory");
  __syncthreads();

  // reduce: s = o%20 spreads 64 consecutive lanes over 20 distinct banks
  for (int o = tid; o < ROWS * SUB_NO; o += 256) {
    const int s = o % 20, row = o / 20;
    float se = 0.f, si = 0.f;
    #pragma unroll
    for (int c = 0; c < 16; ++c) {
      const float* a2 = acc + (row * 16 + c) * 44;
      se += a2[s];
      si += a2[22 + s];
    }
    syn_eT[s * T_DATA + t0 + row] = se;
    syn_iT[s * T_DATA + t0 + row] = si;
  }
}

// ============================================================ conv machinery
// out[t] = sum_j K[j] * X[t + S - j], K zero-padded to 404 taps.
template <int NOUT>
__device__ __forceinline__ void conv_acc(const float* __restrict__ xl,
                                         const float* __restrict__ kg,
                                         int lt, float* __restrict__ acc) {
  constexpr int NW = NOUT + 4;
  float xw[NW];
  #pragma unroll
  for (int r = 0; r < NW / 4; ++r) {
    float4 v = *(const float4*)(xl + lt + 400 + 4 * r);
    xw[4 * r + 0] = v.x; xw[4 * r + 1] = v.y;
    xw[4 * r + 2] = v.z; xw[4 * r + 3] = v.w;
  }
  const float* kp = kg;
  for (int g = 0; g < 100; ++g) {
    float4 kv = *(const float4*)kp; kp += 4;   // uniform -> scalar load
    float kw[4] = {kv.x, kv.y, kv.z, kv.w};
    #pragma unroll
    for (int m = 0; m < 4; ++m)
      #pragma unroll
      for (int j = 0; j < NOUT; ++j)
        acc[j] = fmaf(kw[m], xw[4 + j - m], acc[j]);
    #pragma unroll
    for (int i = NW - 1; i >= 4; --i) xw[i] = xw[i - 4];
    float4 nv = *(const float4*)(xl + lt + 396 - 4 * g);
    xw[0] = nv.x; xw[1] = nv.y; xw[2] = nv.z; xw[3] = nv.w;
  }
  { // final tap group g = 100 (taps 400..403, 401..403 are zero)
    float4 kv = *(const float4*)kp;
    float kw[4] = {kv.x, kv.y, kv.z, kv.w};
    #pragma unroll
    for (int m = 0; m < 4; ++m)
      #pragma unroll
      for (int j = 0; j < NOUT; ++j)
        acc[j] = fmaf(kw[m], xw[4 + j - m], acc[j]);
  }
}

__device__ __forceinline__ void fill_tile(float* __restrict__ xl,
                                          const float* __restrict__ X,
                                          int o, int n) {
  for (int i = threadIdx.x; i < n; i += blockDim.x) {
    int g = o + i;
    xl[i] = (g >= 0 && g < T_DATA) ? X[g] : 0.f;
  }
}

// ---- per-subunit synaptic conv: synT[s][t] = (ke*syn_e)[t] + (ki*syn_i)[t]
__global__ __launch_bounds__(256) void k_syn_conv(
    const float* __restrict__ syn_eT, const float* __restrict__ syn_iT,
    const float* __restrict__ ws, float* __restrict__ synT) {
  const int s = blockIdx.y;
  const int t0 = blockIdx.x * 2048;
  __shared__ __align__(16) float xe[2456];
  __shared__ __align__(16) float xi[2456];
  fill_tile(xe, syn_eT + s * T_DATA, t0 - 404, 2452);
  fill_tile(xi, syn_iT + s * T_DATA, t0 - 404, 2452);
  __syncthreads();
  const int lt = threadIdx.x * 8;
  float acc[8] = {0, 0, 0, 0, 0, 0, 0, 0};
  conv_acc<8>(xe, ws + WS_KE + s * KP, lt, acc);
  conv_acc<8>(xi, ws + WS_KI + s * KP, lt, acc);
  const int t = t0 + lt;
  #pragma unroll
  for (int j = 0; j < 8; ++j)
    if (t + j < T_DATA) synT[s * T_DATA + t + j] = acc[j];
}

// ---- root conv layer 1 with inlined binary-tree tanh recursion.
__global__ __launch_bounds__(256) void k_root1tree(
    const float* __restrict__ synT, const float* __restrict__ Theta,
    const float* __restrict__ W_sub, const float* __restrict__ ws,
    float* __restrict__ h_ws) {
  const int c = blockIdx.y;
  const int t0 = blockIdx.x * 1024;
  __shared__ __align__(16) float xt[1432];
  const int o = t0 + 200 - 404;
  for (int i = threadIdx.x; i < 1428; i += 256) {
    const int t = o + i;
    float h = 0.f;
    if (t >= 0 && t < T_DATA) {
      float ns[SUB_NO];
      #pragma unroll
      for (int q = SUB_NO - 1; q >= 1; --q) {
        float x = synT[q * T_DATA + t] + Theta[q];
        const int c1 = 2 * q + 1, c2 = 2 * q + 2;
        if (c1 < SUB_NO) { float w = W_sub[c1]; x = fmaf(w * w, ns[c1], x); }
        if (c2 < SUB_NO) { float w = W_sub[c2]; x = fmaf(w * w, ns[c2], x); }
        ns[q] = ftanh(x);
      }
      const float w1 = W_sub[1], w2 = W_sub[2];
      h = ftanh(synT[t] + Theta[0] + w1 * w1 * ns[1] + w2 * w2 * ns[2]);
    }
    xt[i] = h;
  }
  __syncthreads();
  const int lt = threadIdx.x * 4;
  float acc[4] = {0, 0, 0, 0};
  conv_acc<4>(xt, ws + WS_K1 + c * KP, lt, acc);
  const int t = t0 + lt;
  #pragma unroll
  for (int j = 0; j < 4; ++j)
    if (t + j < T_DATA) h_ws[c * T_DATA + t + j] = ftanh(acc[j]);
}

// ---- root conv layer 2 partials (y<6) + spike-history conv (y==6)
__global__ __launch_bounds__(256) void k_root2spk(
    const float* __restrict__ h_ws, const float* __restrict__ Z,
    const float* __restrict__ ws, float* __restrict__ part,
    float* __restrict__ outV) {
  const int c = blockIdx.y;
  const int t0 = blockIdx.x * 1024;
  __shared__ __align__(16) float xt[1432];
  const int lt = threadIdx.x * 4;
  float acc[4] = {0, 0, 0, 0};
  if (c < HID_NO) {
    fill_tile(xt, h_ws + c * T_DATA, t0 + 200 - 404, 1428);
    __syncthreads();
    conv_acc<4>(xt, ws + WS_K2 + c * KP, lt, acc);
    const int t = t0 + lt;
    #pragma unroll
    for (int j = 0; j < 4; ++j)
      if (t + j < T_DATA) part[c * T_DATA + t + j] = acc[j];
  } else {
    fill_tile(xt, Z, t0 - 1 - 404, 1428);
    __syncthreads();
    conv_acc<4>(xt, ws + WS_SPK, lt, acc);
    const int t = t0 + lt;
    #pragma unroll
    for (int j = 0; j < 4; ++j)
      if (t + j < T_DATA) outV[t + j] = acc[j];
  }
}

// ---- combine channels + sigmoid -> final_Z
__global__ __launch_bounds__(256) void k_comb(
    const float* __restrict__ part, float* __restrict__ outZ) {
  const int t = blockIdx.x * 256 + threadIdx.x;
  if (t >= T_DATA) return;
  float v = 0.f;
  #pragma unroll
  for (int c = 0; c < HID_NO; ++c) v += part[c * T_DATA + t];
  outZ[t] = __builtin_amdgcn_rcpf(1.f + __expf(-v));
}

// ============================================================ launch
extern "C" void kernel_launch(void* const* d_in, const int* in_sizes, int n_in,
                              void* d_out, int out_size, void* d_ws, size_t ws_size,
                              hipStream_t stream) {
  const float* S_e      = (const float*)d_in[0];
  const float* S_i      = (const float*)d_in[1];
  const float* Z        = (const float*)d_in[2];
  const float* W_syn    = (const float*)d_in[3];
  const float* Tau_syn  = (const float*)d_in[4];
  const float* Delta_syn= (const float*)d_in[5];
  const float* W_sub    = (const float*)d_in[6];
  const float* W_spk    = (const float*)d_in[7];
  const float* Tau_spk  = (const float*)d_in[8];
  const float* Theta    = (const float*)d_in[9];
  const float* W_root_1 = (const float*)d_in[10];
  const float* W_root_2 = (const float*)d_in[11];
  // d_in[12] = C_den (fixed binary tree; hardcoded)
  const float* C_syn_e  = (const float*)d_in[13];
  const float* C_syn_i  = (const float*)d_in[14];
  const float* exp_basis= (const float*)d_in[15];

  float* ws = (float*)d_ws;
  unsigned int* asg_e = (unsigned int*)(ws + WS_ASGE);
  unsigned int* asg_i = (unsigned int*)(ws + WS_ASGI);
  float* out = (float*)d_out;          // [V(50000) | Z(50000) | filters(16040)]

  k_prep<<<3 + SUB_NO + HID_NO, 256, 0, stream>>>(
      W_syn, Tau_syn, Delta_syn, W_spk, Tau_spk, W_root_1, W_root_2,
      C_syn_e, C_syn_i, exp_basis, ws, asg_e, asg_i, out + 2 * T_DATA);

  k_seg<<<T_DATA / ROWS, 256, 0, stream>>>(
      S_e, S_i, asg_e, asg_i, ws + WS_SYN_ET, ws + WS_SYN_IT);

  k_syn_conv<<<dim3(25, SUB_NO), 256, 0, stream>>>(
      ws + WS_SYN_ET, ws + WS_SYN_IT, ws, ws + WS_SYNT);

  k_root1tree<<<dim3(49, HID_NO), 256, 0, stream>>>(
      ws + WS_SYNT, Theta, W_sub, ws, ws + WS_H);

  k_root2spk<<<dim3(49, HID_NO + 1), 256, 0, stream>>>(
      ws + WS_H, Z, ws, ws + WS_PART, out);

  k_comb<<<(T_DATA + 255) / 256, 256, 0, stream>>>(ws + WS_PART, out + T_DATA);
}

// Round 8
// 231.826 us; speedup vs baseline: 3.0909x; 3.0278x over previous
//
#include <hip/hip_runtime.h>
#include <math.h>

#define T_DATA 50000
#define N_E 2000
#define N_I 200
#define SUB_NO 20
#define T_NO 401
#define KP 404            // zero-padded kernel length (multiple of 4)
#define EXP_NO 81
#define HID_NO 6
#define KT_E 63           // ceil(2000/32) k-tiles for E
#define KT_I 7            // ceil(200/32)  k-tiles for I

// ---- workspace layout (float offsets) ----
#define WS_SYN_ET   0              // [20][T]
#define WS_SYN_IT   1000000        // [20][T]
#define WS_SYNT     2000000        // [20][T]  E-conv + I-conv sum
#define WS_H        3000000        // [6][T]
#define WS_PART     3300000        // [6][T]
#define WS_KE       3600000        // [20][404]
#define WS_KI       3608080        // [20][404]
#define WS_K1       3616160        // [6][404]
#define WS_K2       3618584        // [6][404]
#define WS_SPK      3621008        // [404]
#define WS_BFE      3621412        // bf16 B-fragments E: 63*2*64 uint4 (129KB)
#define WS_BFI      3653668        // bf16 B-fragments I: 7*2*64 uint4

typedef __attribute__((ext_vector_type(8))) short bf16x8;   // 8 bf16 = 4 VGPR
typedef __attribute__((ext_vector_type(4))) float f32x4;

__device__ __forceinline__ float ftanh(float x) {
  float e = __expf(2.f * x);
  return 1.f - 2.f * __builtin_amdgcn_rcpf(e + 1.f);
}

// round-to-nearest-even f32 -> bf16 bits (sign-agnostic bit trick)
__device__ __forceinline__ unsigned short bf16_rne(float x) {
  unsigned int u = __float_as_uint(x);
  u += 0x7FFFu + ((u >> 16) & 1u);
  return (unsigned short)(u >> 16);
}

// ============================================================ prep
__global__ __launch_bounds__(256) void k_prep(
    const float* __restrict__ W_syn, const float* __restrict__ Tau_syn,
    const float* __restrict__ Delta_syn, const float* __restrict__ W_spk,
    const float* __restrict__ Tau_spk, const float* __restrict__ W_root_1,
    const float* __restrict__ W_root_2, const float* __restrict__ C_syn_e,
    const float* __restrict__ C_syn_i, const float* __restrict__ exp_basis,
    float* __restrict__ ws, float* __restrict__ out_filters) {
  const int bid = blockIdx.x, tid = threadIdx.x;
  if (bid < 2) {
    // B-fragments for E: entry f = (kt*2+n)*64+lane; elem j: k=kt*32+(lane>>4)*8+j,
    // s=n*16+(lane&15); value = one-hot mask C_syn_e[s][k] as bf16 (0 or 1.0).
    uint4* bf = (uint4*)(ws + WS_BFE);
    for (int f = tid + (bid == 1 ? 256 : 0); f < KT_E * 2 * 64; f += 512) {
      const int lane = f & 63, nk = f >> 6, n = nk & 1, kt = nk >> 1;
      const int s = n * 16 + (lane & 15);
      unsigned int v[8];
      #pragma unroll
      for (int j = 0; j < 8; ++j) {
        const int k = kt * 32 + ((lane >> 4) << 3) + j;
        v[j] = (k < N_E && s < SUB_NO && C_syn_e[s * N_E + k] > 0.5f) ? 0x3F80u : 0u;
      }
      uint4 u;
      u.x = v[0] | (v[1] << 16); u.y = v[2] | (v[3] << 16);
      u.z = v[4] | (v[5] << 16); u.w = v[6] | (v[7] << 16);
      bf[f] = u;
    }
  } else if (bid == 2) {                // spike-history kernel
    const float tau = Tau_spk[0], w = W_spk[0];
    const float it2 = 1.f / (tau * tau);
    for (int t = tid; t < KP; t += 256) {
      float v = 0.f;
      if (t < T_NO) { float tt = (float)t * it2; v = tt * __expf(-tt) * w * w; }
      ws[WS_SPK + t] = v;
    }
  } else if (bid < 3 + SUB_NO) {        // synaptic E/I kernels + out_filters
    const int s = bid - 3;
    const float we = W_syn[s * 2], wi = W_syn[s * 2 + 1];
    const float te = Tau_syn[s * 2], ti = Tau_syn[s * 2 + 1];
    const float de = Delta_syn[s * 2], di = Delta_syn[s * 2 + 1];
    const float ie2 = 1.f / (te * te), ii2 = 1.f / (ti * ti);
    for (int t = tid; t < KP; t += 256) {
      float ve = 0.f, vi = 0.f;
      if (t < T_NO) {
        float xe = fmaxf((float)t - de, 0.f) * ie2;
        float xi = fmaxf((float)t - di, 0.f) * ii2;
        ve = xe * __expf(-xe) * we * we;
        vi = -(xi * __expf(-xi) * wi * wi);
        out_filters[s * T_NO + t] = ve;
        out_filters[(SUB_NO + s) * T_NO + t] = vi;
      }
      ws[WS_KE + s * KP + t] = ve;
      ws[WS_KI + s * KP + t] = vi;
    }
  } else if (bid < 3 + SUB_NO + HID_NO) { // root conv kernels
    const int h = bid - (3 + SUB_NO);
    for (int t = tid; t < KP; t += 256) {
      float v1 = 0.f, v2 = 0.f;
      if (t < T_NO) {
        for (int b = 0; b < EXP_NO; ++b) {
          float bb = exp_basis[b * T_NO + t];
          v1 = fmaf(W_root_1[h * EXP_NO + b], bb, v1);
          v2 = fmaf(W_root_2[h * EXP_NO + b], bb, v2);
        }
      }
      ws[WS_K1 + h * KP + t] = v1;
      ws[WS_K2 + h * KP + t] = v2;
    }
  } else {                              // B-fragments for I
    uint4* bf = (uint4*)(ws + WS_BFI);
    for (int f = tid; f < KT_I * 2 * 64; f += 256) {
      const int lane = f & 63, nk = f >> 6, n = nk & 1, kt = nk >> 1;
      const int s = n * 16 + (lane & 15);
      unsigned int v[8];
      #pragma unroll
      for (int j = 0; j < 8; ++j) {
        const int k = kt * 32 + ((lane >> 4) << 3) + j;
        v[j] = (k < N_I && s < SUB_NO && C_syn_i[s * N_I + k] > 0.5f) ? 0x3F80u : 0u;
      }
      uint4 u;
      u.x = v[0] | (v[1] << 16); u.y = v[2] | (v[3] << 16);
      u.z = v[4] | (v[5] << 16); u.w = v[6] | (v[7] << 16);
      bf[f] = u;
    }
  }
}

// ============================================================ segmented sums via MFMA
// syn = S @ M (M one-hot): wave owns a 16-row panel; K swept in 32-col tiles.
// A = f32 rows split hi/lo bf16 (exact to ~2^-18 rel); B = precomputed one-hot
// fragments. Same (lane>>4,reg)->k bijection on A and B makes the result
// invariant to the true HW k-permutation. No LDS, no atomics, no syncs.
__global__ __launch_bounds__(256) void k_segmm(
    const float* __restrict__ S_e, const float* __restrict__ S_i,
    const float* __restrict__ ws,
    float* __restrict__ syn_eT, float* __restrict__ syn_iT) {
  const int tid = threadIdx.x;
  const int wave = tid >> 6, lane = tid & 63;
  const int mrow = lane & 15;        // A: M-index
  const int kgrp = lane >> 4;        // A/B: k-group (k = kgrp*8 + j)
  const int trow = blockIdx.x * 64 + wave * 16 + mrow;
  const int tl = trow < T_DATA ? trow : T_DATA - 1;   // clamp (discard at store)
  const bf16x8* __restrict__ bfE = (const bf16x8*)(ws + WS_BFE);
  const bf16x8* __restrict__ bfI = (const bf16x8*)(ws + WS_BFI);

  f32x4 accE0 = {0.f, 0.f, 0.f, 0.f}, accE1 = accE0;
  f32x4 accI0 = accE0, accI1 = accE0;

  // ---------------- E panel: 63 k-tiles over 2000 cols
  {
    const float* rowp = S_e + (size_t)tl * N_E;
    for (int kt = 0; kt < KT_E; ++kt) {
      const int col0 = kt * 32 + kgrp * 8;
      float x[8];
      if (col0 + 8 <= N_E) {
        float4 va = *(const float4*)(rowp + col0);
        float4 vb = *(const float4*)(rowp + col0 + 4);
        x[0] = va.x; x[1] = va.y; x[2] = va.z; x[3] = va.w;
        x[4] = vb.x; x[5] = vb.y; x[6] = vb.z; x[7] = vb.w;
      } else {
        #pragma unroll
        for (int j = 0; j < 8; ++j) {
          const int c = col0 + j;
          x[j] = (c < N_E) ? rowp[c] : 0.f;
        }
      }
      bf16x8 ahi, alo;
      #pragma unroll
      for (int j = 0; j < 8; ++j) {
        unsigned short h = bf16_rne(x[j]);
        ahi[j] = (short)h;
        float res = x[j] - __uint_as_float((unsigned int)h << 16);
        alo[j] = (short)bf16_rne(res);
      }
      bf16x8 b0 = bfE[(kt * 2 + 0) * 64 + lane];
      bf16x8 b1 = bfE[(kt * 2 + 1) * 64 + lane];
      accE0 = __builtin_amdgcn_mfma_f32_16x16x32_bf16(ahi, b0, accE0, 0, 0, 0);
      accE0 = __builtin_amdgcn_mfma_f32_16x16x32_bf16(alo, b0, accE0, 0, 0, 0);
      accE1 = __builtin_amdgcn_mfma_f32_16x16x32_bf16(ahi, b1, accE1, 0, 0, 0);
      accE1 = __builtin_amdgcn_mfma_f32_16x16x32_bf16(alo, b1, accE1, 0, 0, 0);
    }
  }
  // ---------------- I panel: 7 k-tiles over 200 cols
  {
    const float* rowp = S_i + (size_t)tl * N_I;
    for (int kt = 0; kt < KT_I; ++kt) {
      const int col0 = kt * 32 + kgrp * 8;
      float x[8];
      if (col0 + 8 <= N_I) {
        float4 va = *(const float4*)(rowp + col0);
        float4 vb = *(const float4*)(rowp + col0 + 4);
        x[0] = va.x; x[1] = va.y; x[2] = va.z; x[3] = va.w;
        x[4] = vb.x; x[5] = vb.y; x[6] = vb.z; x[7] = vb.w;
      } else {
        #pragma unroll
        for (int j = 0; j < 8; ++j) {
          const int c = col0 + j;
          x[j] = (c < N_I) ? rowp[c] : 0.f;
        }
      }
      bf16x8 ahi, alo;
      #pragma unroll
      for (int j = 0; j < 8; ++j) {
        unsigned short h = bf16_rne(x[j]);
        ahi[j] = (short)h;
        float res = x[j] - __uint_as_float((unsigned int)h << 16);
        alo[j] = (short)bf16_rne(res);
      }
      bf16x8 b0 = bfI[(kt * 2 + 0) * 64 + lane];
      bf16x8 b1 = bfI[(kt * 2 + 1) * 64 + lane];
      accI0 = __builtin_amdgcn_mfma_f32_16x16x32_bf16(ahi, b0, accI0, 0, 0, 0);
      accI0 = __builtin_amdgcn_mfma_f32_16x16x32_bf16(alo, b0, accI0, 0, 0, 0);
      accI1 = __builtin_amdgcn_mfma_f32_16x16x32_bf16(ahi, b1, accI1, 0, 0, 0);
      accI1 = __builtin_amdgcn_mfma_f32_16x16x32_bf16(alo, b1, accI1, 0, 0, 0);
    }
  }

  // ---------------- store: D[row][col], col=lane&15 (=subunit), row=(lane>>4)*4+j
  const int s0 = lane & 15;          // ntile0: subunits 0..15
  const int s1 = 16 + s0;            // ntile1: subunits 16..19 valid
  const int tout = blockIdx.x * 64 + wave * 16 + kgrp * 4;
  #pragma unroll
  for (int j = 0; j < 4; ++j) {
    const int t = tout + j;
    if (t < T_DATA) {
      syn_eT[s0 * T_DATA + t] = accE0[j];
      syn_iT[s0 * T_DATA + t] = accI0[j];
      if (s1 < SUB_NO) {
        syn_eT[s1 * T_DATA + t] = accE1[j];
        syn_iT[s1 * T_DATA + t] = accI1[j];
      }
    }
  }
}

// ============================================================ conv machinery
// out[t] = sum_j K[j] * X[t + S - j], K zero-padded to 404 taps.
template <int NOUT>
__device__ __forceinline__ void conv_acc(const float* __restrict__ xl,
                                         const float* __restrict__ kg,
                                         int lt, float* __restrict__ acc) {
  constexpr int NW = NOUT + 4;
  float xw[NW];
  #pragma unroll
  for (int r = 0; r < NW / 4; ++r) {
    float4 v = *(const float4*)(xl + lt + 400 + 4 * r);
    xw[4 * r + 0] = v.x; xw[4 * r + 1] = v.y;
    xw[4 * r + 2] = v.z; xw[4 * r + 3] = v.w;
  }
  const float* kp = kg;
  for (int g = 0; g < 100; ++g) {
    float4 kv = *(const float4*)kp; kp += 4;   // uniform -> scalar load
    float kw[4] = {kv.x, kv.y, kv.z, kv.w};
    #pragma unroll
    for (int m = 0; m < 4; ++m)
      #pragma unroll
      for (int j = 0; j < NOUT; ++j)
        acc[j] = fmaf(kw[m], xw[4 + j - m], acc[j]);
    #pragma unroll
    for (int i = NW - 1; i >= 4; --i) xw[i] = xw[i - 4];
    float4 nv = *(const float4*)(xl + lt + 396 - 4 * g);
    xw[0] = nv.x; xw[1] = nv.y; xw[2] = nv.z; xw[3] = nv.w;
  }
  { // final tap group g = 100 (taps 400..403, 401..403 are zero)
    float4 kv = *(const float4*)kp;
    float kw[4] = {kv.x, kv.y, kv.z, kv.w};
    #pragma unroll
    for (int m = 0; m < 4; ++m)
      #pragma unroll
      for (int j = 0; j < NOUT; ++j)
        acc[j] = fmaf(kw[m], xw[4 + j - m], acc[j]);
  }
}

__device__ __forceinline__ void fill_tile(float* __restrict__ xl,
                                          const float* __restrict__ X,
                                          int o, int n) {
  for (int i = threadIdx.x; i < n; i += blockDim.x) {
    int g = o + i;
    xl[i] = (g >= 0 && g < T_DATA) ? X[g] : 0.f;
  }
}

// ---- per-subunit synaptic conv: synT[s][t] = (ke*syn_e)[t] + (ki*syn_i)[t]
__global__ __launch_bounds__(256) void k_syn_conv(
    const float* __restrict__ syn_eT, const float* __restrict__ syn_iT,
    const float* __restrict__ ws, float* __restrict__ synT) {
  const int s = blockIdx.y;
  const int t0 = blockIdx.x * 2048;
  __shared__ __align__(16) float xe[2456];
  __shared__ __align__(16) float xi[2456];
  fill_tile(xe, syn_eT + s * T_DATA, t0 - 404, 2452);
  fill_tile(xi, syn_iT + s * T_DATA, t0 - 404, 2452);
  __syncthreads();
  const int lt = threadIdx.x * 8;
  float acc[8] = {0, 0, 0, 0, 0, 0, 0, 0};
  conv_acc<8>(xe, ws + WS_KE + s * KP, lt, acc);
  conv_acc<8>(xi, ws + WS_KI + s * KP, lt, acc);
  const int t = t0 + lt;
  #pragma unroll
  for (int j = 0; j < 8; ++j)
    if (t + j < T_DATA) synT[s * T_DATA + t + j] = acc[j];
}

// ---- root conv layer 1 with inlined binary-tree tanh recursion.
__global__ __launch_bounds__(256) void k_root1tree(
    const float* __restrict__ synT, const float* __restrict__ Theta,
    const float* __restrict__ W_sub, const float* __restrict__ ws,
    float* __restrict__ h_ws) {
  const int c = blockIdx.y;
  const int t0 = blockIdx.x * 1024;
  __shared__ __align__(16) float xt[1432];
  const int o = t0 + 200 - 404;
  for (int i = threadIdx.x; i < 1428; i += 256) {
    const int t = o + i;
    float h = 0.f;
    if (t >= 0 && t < T_DATA) {
      float ns[SUB_NO];
      #pragma unroll
      for (int q = SUB_NO - 1; q >= 1; --q) {
        float x = synT[q * T_DATA + t] + Theta[q];
        const int c1 = 2 * q + 1, c2 = 2 * q + 2;
        if (c1 < SUB_NO) { float w = W_sub[c1]; x = fmaf(w * w, ns[c1], x); }
        if (c2 < SUB_NO) { float w = W_sub[c2]; x = fmaf(w * w, ns[c2], x); }
        ns[q] = ftanh(x);
      }
      const float w1 = W_sub[1], w2 = W_sub[2];
      h = ftanh(synT[t] + Theta[0] + w1 * w1 * ns[1] + w2 * w2 * ns[2]);
    }
    xt[i] = h;
  }
  __syncthreads();
  const int lt = threadIdx.x * 4;
  float acc[4] = {0, 0, 0, 0};
  conv_acc<4>(xt, ws + WS_K1 + c * KP, lt, acc);
  const int t = t0 + lt;
  #pragma unroll
  for (int j = 0; j < 4; ++j)
    if (t + j < T_DATA) h_ws[c * T_DATA + t + j] = ftanh(acc[j]);
}

// ---- root conv layer 2 partials (y<6) + spike-history conv (y==6)
__global__ __launch_bounds__(256) void k_root2spk(
    const float* __restrict__ h_ws, const float* __restrict__ Z,
    const float* __restrict__ ws, float* __restrict__ part,
    float* __restrict__ outV) {
  const int c = blockIdx.y;
  const int t0 = blockIdx.x * 1024;
  __shared__ __align__(16) float xt[1432];
  const int lt = threadIdx.x * 4;
  float acc[4] = {0, 0, 0, 0};
  if (c < HID_NO) {
    fill_tile(xt, h_ws + c * T_DATA, t0 + 200 - 404, 1428);
    __syncthreads();
    conv_acc<4>(xt, ws + WS_K2 + c * KP, lt, acc);
    const int t = t0 + lt;
    #pragma unroll
    for (int j = 0; j < 4; ++j)
      if (t + j < T_DATA) part[c * T_DATA + t + j] = acc[j];
  } else {
    fill_tile(xt, Z, t0 - 1 - 404, 1428);
    __syncthreads();
    conv_acc<4>(xt, ws + WS_SPK, lt, acc);
    const int t = t0 + lt;
    #pragma unroll
    for (int j = 0; j < 4; ++j)
      if (t + j < T_DATA) outV[t + j] = acc[j];
  }
}

// ---- combine channels + sigmoid -> final_Z
__global__ __launch_bounds__(256) void k_comb(
    const float* __restrict__ part, float* __restrict__ outZ) {
  const int t = blockIdx.x * 256 + threadIdx.x;
  if (t >= T_DATA) return;
  float v = 0.f;
  #pragma unroll
  for (int c = 0; c < HID_NO; ++c) v += part[c * T_DATA + t];
  outZ[t] = __builtin_amdgcn_rcpf(1.f + __expf(-v));
}

// ============================================================ launch
extern "C" void kernel_launch(void* const* d_in, const int* in_sizes, int n_in,
                              void* d_out, int out_size, void* d_ws, size_t ws_size,
                              hipStream_t stream) {
  const float* S_e      = (const float*)d_in[0];
  const float* S_i      = (const float*)d_in[1];
  const float* Z        = (const float*)d_in[2];
  const float* W_syn    = (const float*)d_in[3];
  const float* Tau_syn  = (const float*)d_in[4];
  const float* Delta_syn= (const float*)d_in[5];
  const float* W_sub    = (const float*)d_in[6];
  const float* W_spk    = (const float*)d_in[7];
  const float* Tau_spk  = (const float*)d_in[8];
  const float* Theta    = (const float*)d_in[9];
  const float* W_root_1 = (const float*)d_in[10];
  const float* W_root_2 = (const float*)d_in[11];
  // d_in[12] = C_den (fixed binary tree; hardcoded)
  const float* C_syn_e  = (const float*)d_in[13];
  const float* C_syn_i  = (const float*)d_in[14];
  const float* exp_basis= (const float*)d_in[15];

  float* ws = (float*)d_ws;
  float* out = (float*)d_out;          // [V(50000) | Z(50000) | filters(16040)]

  k_prep<<<3 + SUB_NO + HID_NO + 1, 256, 0, stream>>>(
      W_syn, Tau_syn, Delta_syn, W_spk, Tau_spk, W_root_1, W_root_2,
      C_syn_e, C_syn_i, exp_basis, ws, out + 2 * T_DATA);

  k_segmm<<<(T_DATA + 63) / 64, 256, 0, stream>>>(
      S_e, S_i, ws, ws + WS_SYN_ET, ws + WS_SYN_IT);

  k_syn_conv<<<dim3(25, SUB_NO), 256, 0, stream>>>(
      ws + WS_SYN_ET, ws + WS_SYN_IT, ws, ws + WS_SYNT);

  k_root1tree<<<dim3(49, HID_NO), 256, 0, stream>>>(
      ws + WS_SYNT, Theta, W_sub, ws, ws + WS_H);

  k_root2spk<<<dim3(49, HID_NO + 1), 256, 0, stream>>>(
      ws + WS_H, Z, ws, ws + WS_PART, out);

  k_comb<<<(T_DATA + 255) / 256, 256, 0, stream>>>(ws + WS_PART, out + T_DATA);
}